// Round 7
// baseline (224.135 us; speedup 1.0000x reference)
//
#include <hip/hip_runtime.h>

// B=4, S=4096, D_IN=1024, D_QK=D_V=64
// out = softmax(relu(XWq+bq) @ relu(XWk+bk)^T) @ relu(XWv+bv) * mask

typedef short s16x8 __attribute__((ext_vector_type(8)));   // 8 bf16 (4 VGPRs) MFMA frag
typedef float fx4   __attribute__((ext_vector_type(4)));   // MFMA accum frag
typedef unsigned short u16x4 __attribute__((ext_vector_type(4)));

#define LOG2E 1.4426950408889634f

__device__ __forceinline__ unsigned short f2bf(float x) {   // fp32 -> bf16 RTN
    unsigned int u = __float_as_uint(x);
    u += 0x7FFFu + ((u >> 16) & 1u);
    return (unsigned short)(u >> 16);
}
__device__ __forceinline__ float bf2f(unsigned short b) {
    return __uint_as_float(((unsigned int)b) << 16);
}

// ---------------------------------------------------------------------------
// Kernel 1: split W{q,k,v} [1024][64] fp32 into W^T hi/lo bf16 [3][64][1024].
// LDS tile-transpose; coalesced reads, contiguous 32 B runs along k going out.
// grid (3 y, 16 k-tiles) x 256.  (unchanged)
// ---------------------------------------------------------------------------
__global__ __launch_bounds__(256) void prep_w_kernel(
    const float* __restrict__ Wq, const float* __restrict__ Wk, const float* __restrict__ Wv,
    unsigned short* __restrict__ wt_hi, unsigned short* __restrict__ wt_lo)
{
    __shared__ __align__(16) unsigned short sh[64][72];   // [c][k_local]
    __shared__ __align__(16) unsigned short sl[64][72];

    const int y  = blockIdx.x;
    const int kt = blockIdx.y;
    const float* W = (y == 0) ? Wq : (y == 1) ? Wk : Wv;
    const int t  = threadIdx.x;

    const int kl = t >> 2;
    const int c0 = (t & 3) * 16;
    const float* src = W + (size_t)(kt * 64 + kl) * 64 + c0;
    #pragma unroll
    for (int j = 0; j < 4; j++) {
        fx4 v = *(const fx4*)(src + j * 4);
        #pragma unroll
        for (int i = 0; i < 4; i++) {
            float x = v[i];
            unsigned short h = f2bf(x);
            unsigned short l = f2bf(x - bf2f(h));
            sh[c0 + j * 4 + i][kl] = h;
            sl[c0 + j * 4 + i][kl] = l;
        }
    }
    __syncthreads();

    const int c  = t >> 2;
    const int k0 = (t & 3) * 16;
    size_t o = (size_t)(y * 64 + c) * 1024 + kt * 64 + k0;
    *(s16x8*)(wt_hi + o)     = *(const s16x8*)&sh[c][k0];
    *(s16x8*)(wt_hi + o + 8) = *(const s16x8*)&sh[c][k0 + 8];
    *(s16x8*)(wt_lo + o)     = *(const s16x8*)&sl[c][k0];
    *(s16x8*)(wt_lo + o + 8) = *(const s16x8*)&sl[c][k0 + 8];
}

// ---------------------------------------------------------------------------
// Kernel 2 (v6): FUSED q/k/v projection, B in LDS. Grid 256 (one 64-row
// m-tile per block, 1 block/CU), block 768 = 12 waves = 2 row-groups x
// 6 col-groups ({q,k,v} x 2 col-halves). X converted to hi/lo bf16 ONCE per
// m-tile; W relayed global->reg(depth 2)->LDS, X depth 4 (v2-proven relay).
// 32x32 wave tiles. Measured: dropped proj below 41.6us (out of top-5).
// (unchanged)
// ---------------------------------------------------------------------------
__global__ __launch_bounds__(768, 3) void proj_kernel(
    const float* __restrict__ X,
    const unsigned short* __restrict__ wt_hi, const unsigned short* __restrict__ wt_lo,
    const float* __restrict__ bq, const float* __restrict__ bk, const float* __restrict__ bv,
    unsigned short* __restrict__ q_hi, unsigned short* __restrict__ q_lo,
    unsigned short* __restrict__ k_bf, unsigned short* __restrict__ vt_g)
{
    __shared__ __align__(16) unsigned short a_hi[64][72];    // X tile hi (+8 pad)
    __shared__ __align__(16) unsigned short a_lo[64][72];    // X tile lo
    __shared__ __align__(16) unsigned short bsh[192][72];    // W^T all-y hi [col][k]
    __shared__ __align__(16) unsigned short bsl[192][72];    // W^T all-y lo

    const int tid  = threadIdx.x;
    const int lane = tid & 63;
    const int w    = tid >> 6;      // 0..11
    const int quad = lane >> 4;
    const int l15  = lane & 15;
    const int rowg = w & 1;         // 32-row group
    const int colg = w >> 1;        // 0..5 = {q,k,v} x {col half}
    const int y    = colg >> 1;     // 0=q 1=k 2=v
    const int ch   = colg & 1;      // 32-col half within y

    const int m0 = blockIdx.x * 64;

    fx4 acc[2][2];                  // [sub 16 rows][nt 16 cols]
    #pragma unroll
    for (int i = 0; i < 2; i++)
        #pragma unroll
        for (int j = 0; j < 2; j++) acc[i][j] = (fx4){0.f, 0.f, 0.f, 0.f};

    // X staging: threads 0..511, 8 floats each (rows xrow, xrow+32)
    const int xrow = tid >> 4;        // 0..31 (tid<512)
    const int xoff = (tid & 15) * 4;
    const float* xb0 = X + (size_t)(m0 + xrow) * 1024 + xoff;
    const float* xb1 = X + (size_t)(m0 + xrow + 32) * 1024 + xoff;

    // W staging: all 768 threads, 32 B (hi) + 32 B (lo) each per kc
    const int wrow = tid >> 2;        // 0..191
    const int wk   = (tid & 3) * 16;  // k-offset (shorts)
    const size_t wb = (size_t)wrow * 1024 + wk;

    // register relays: X depth 4, W depth 2 (v2-proven pattern)
    fx4   xr[4][2];
    s16x8 wrh[2][2], wrl[2][2];
    if (tid < 512) {
        #pragma unroll
        for (int d = 0; d < 4; d++) {
            xr[d][0] = *(const fx4*)(xb0 + d * 64);
            xr[d][1] = *(const fx4*)(xb1 + d * 64);
        }
    }
    #pragma unroll
    for (int d = 0; d < 2; d++) {
        wrh[d][0] = *(const s16x8*)(wt_hi + wb + d * 64);
        wrh[d][1] = *(const s16x8*)(wt_hi + wb + d * 64 + 8);
        wrl[d][0] = *(const s16x8*)(wt_lo + wb + d * 64);
        wrl[d][1] = *(const s16x8*)(wt_lo + wb + d * 64 + 8);
    }

    #pragma unroll 4
    for (int kc = 0; kc < 16; kc++) {
        if (kc) __syncthreads();   // prev iter's LDS readers done
        if (tid < 512) {
            #pragma unroll
            for (int i = 0; i < 2; i++) {
                fx4 xv = xr[kc & 3][i];
                unsigned short h0 = f2bf(xv.x), h1 = f2bf(xv.y), h2 = f2bf(xv.z), h3 = f2bf(xv.w);
                unsigned short l0 = f2bf(xv.x - bf2f(h0)), l1 = f2bf(xv.y - bf2f(h1));
                unsigned short l2 = f2bf(xv.z - bf2f(h2)), l3 = f2bf(xv.w - bf2f(h3));
                *(u16x4*)&a_hi[xrow + i * 32][xoff] = (u16x4){h0, h1, h2, h3};
                *(u16x4*)&a_lo[xrow + i * 32][xoff] = (u16x4){l0, l1, l2, l3};
            }
        }
        *(s16x8*)&bsh[wrow][wk]     = wrh[kc & 1][0];
        *(s16x8*)&bsh[wrow][wk + 8] = wrh[kc & 1][1];
        *(s16x8*)&bsl[wrow][wk]     = wrl[kc & 1][0];
        *(s16x8*)&bsl[wrow][wk + 8] = wrl[kc & 1][1];
        __syncthreads();

        // refill relays (latency hides behind this iter's frag reads + MFMAs)
        if (tid < 512 && kc < 12) {
            xr[kc & 3][0] = *(const fx4*)(xb0 + (kc + 4) * 64);
            xr[kc & 3][1] = *(const fx4*)(xb1 + (kc + 4) * 64);
        }
        if (kc < 14) {
            wrh[kc & 1][0] = *(const s16x8*)(wt_hi + wb + (kc + 2) * 64);
            wrh[kc & 1][1] = *(const s16x8*)(wt_hi + wb + (kc + 2) * 64 + 8);
            wrl[kc & 1][0] = *(const s16x8*)(wt_lo + wb + (kc + 2) * 64);
            wrl[kc & 1][1] = *(const s16x8*)(wt_lo + wb + (kc + 2) * 64 + 8);
        }

        // A frags (32 rows: sub=0,1)
        s16x8 ah[2][2], al[2][2];
        #pragma unroll
        for (int sub = 0; sub < 2; sub++)
            #pragma unroll
            for (int ks = 0; ks < 2; ks++) {
                const int r = rowg * 32 + sub * 16 + l15;
                ah[sub][ks] = *(const s16x8*)&a_hi[r][ks * 32 + quad * 8];
                al[sub][ks] = *(const s16x8*)&a_lo[r][ks * 32 + quad * 8];
            }
        #pragma unroll
        for (int nt = 0; nt < 2; nt++) {
            const int br = colg * 32 + nt * 16 + l15;
            #pragma unroll
            for (int ks = 0; ks < 2; ks++) {
                s16x8 bh = *(const s16x8*)&bsh[br][ks * 32 + quad * 8];
                s16x8 bl = *(const s16x8*)&bsl[br][ks * 32 + quad * 8];
                #pragma unroll
                for (int sub = 0; sub < 2; sub++) {
                    acc[sub][nt] = __builtin_amdgcn_mfma_f32_16x16x32_bf16(ah[sub][ks], bh, acc[sub][nt], 0, 0, 0);
                    acc[sub][nt] = __builtin_amdgcn_mfma_f32_16x16x32_bf16(ah[sub][ks], bl, acc[sub][nt], 0, 0, 0);
                    acc[sub][nt] = __builtin_amdgcn_mfma_f32_16x16x32_bf16(al[sub][ks], bh, acc[sub][nt], 0, 0, 0);
                }
            }
        }
    }
    __syncthreads();   // all MFMA LDS reads done before vtr alias writes

    // epilogue: bias + relu; q -> hi/lo, k -> bf16, v -> transpose via LDS
    const float* bias = (y == 0) ? bq : (y == 1) ? bk : bv;
    const int b   = m0 >> 12;
    const int s0b = m0 & 4095;
    unsigned short* vtr = &a_hi[0][0];  // alias: [64 d][72]

    #pragma unroll
    for (int sub = 0; sub < 2; sub++)
        #pragma unroll
        for (int nt = 0; nt < 2; nt++) {
            const int col = ch * 32 + nt * 16 + l15;
            const float bb = bias[col];
            const int rloc = rowg * 32 + sub * 16 + quad * 4;
            #pragma unroll
            for (int r = 0; r < 4; r++) {
                float v = fmaxf(acc[sub][nt][r] + bb, 0.f);
                size_t grow = (size_t)(m0 + rloc + r);
                if (y == 0) {
                    unsigned short h = f2bf(v);
                    unsigned short l = f2bf(v - bf2f(h));
                    q_hi[grow * 64 + col] = h;
                    q_lo[grow * 64 + col] = l;
                } else if (y == 1) {
                    k_bf[grow * 64 + col] = f2bf(v);
                } else {
                    vtr[col * 72 + rloc + r] = f2bf(v);  // transpose via LDS
                }
            }
        }
    __syncthreads();   // v-waves' vtr writes visible to storing threads
    if (tid < 512) {
        int row = tid >> 3;          // d 0..63
        int off = (tid & 7) * 8;     // s chunk
        s16x8 vv = *(const s16x8*)&vtr[row * 72 + off];
        *(s16x8*)(vt_g + (size_t)(b * 64 + row) * 4096 + s0b + off) = vv;
    }
}

// ---------------------------------------------------------------------------
// Kernel 3 (v8): fused attention. Round-6 counters falsified "LDS-read
// bound" (halving reads was neutral): MfmaUtil 23 + VALU 35 + Occ 22 =>
// ~70% idle = latency/serialization. The serial segment per tile was
// {stage-write LDS -> barrier -> compute -> barrier}. v8: KVBLK 32 with
// TRUE double-buffered kt/vt -- the regs->LDS write for tile t+1 lands in
// the other buffer DURING compute of tile t; ONE barrier per tile; T14
// global-load issue stays at loop top (latency under compute). Key order
// (16 x 32-key tiles == 8 x (32+32)) and per-output MFMA/exp/add order are
// IDENTICAL to v7 => bit-identical results. 4 waves x 32 q-rows = 128 q,
// grid 32 x 8 x 4 = 1024. LDS 29.7 KB; launch_bounds(256,4) caps VGPR 128
// (est ~110, prefetch regs live), 4 blocks/CU.
// ---------------------------------------------------------------------------
__global__ __launch_bounds__(256, 4) void attn_kernel(
    const unsigned short* __restrict__ q_hi, const unsigned short* __restrict__ q_lo,
    const unsigned short* __restrict__ k_bf, const unsigned short* __restrict__ vt_g,
    unsigned short* __restrict__ pOb, float* __restrict__ pL)
{
    __shared__ __align__(16) unsigned short kt[2][32][72];   // [dbuf][key][dim]
    __shared__ __align__(16) unsigned short vt[2][64][40];   // [dbuf][dim][key+8]
    __shared__ __align__(16) unsigned short pt[4][32][40];   // per-wave P [q][key]

    const int tid  = threadIdx.x;
    const int lane = tid & 63;
    const int w    = tid >> 6;           // 0..3
    const int quad = lane >> 4;
    const int l15  = lane & 15;
    const int ck   = blockIdx.y;         // key chunk (512 keys = 16 tiles x 32)
    const int b    = blockIdx.z;
    const int q0   = blockIdx.x * 128;   // within batch

    // Q fragments for both 16-row subtiles (A layout: m=lane&15, k=quad*8+j)
    const size_t qbase = ((size_t)b * 4096 + q0 + w * 32 + l15) * 64 + quad * 8;
    s16x8 qh[2][2], ql[2][2];            // [sub][k-half]
    #pragma unroll
    for (int sub = 0; sub < 2; sub++) {
        qh[sub][0] = *(const s16x8*)(q_hi + qbase + sub * 1024);
        qh[sub][1] = *(const s16x8*)(q_hi + qbase + sub * 1024 + 32);
        ql[sub][0] = *(const s16x8*)(q_lo + qbase + sub * 1024);
        ql[sub][1] = *(const s16x8*)(q_lo + qbase + sub * 1024 + 32);
    }

    fx4 accO[2][4];
    #pragma unroll
    for (int sub = 0; sub < 2; sub++)
        #pragma unroll
        for (int nt = 0; nt < 4; nt++) accO[sub][nt] = (fx4){0.f, 0.f, 0.f, 0.f};
    float lsum[2][4] = {{0.f, 0.f, 0.f, 0.f}, {0.f, 0.f, 0.f, 0.f}};

    const unsigned short* kgb = k_bf + (size_t)b * 4096 * 64;  // [s][64]
    const unsigned short* vgb = vt_g + (size_t)b * 64 * 4096;  // [d][s]

    // staging (per 32-key tile, 4 KB each of K and V^T; 16 B per thread each)
    const int krow = tid >> 3;            // 0..31 (key)
    const int koff = (tid & 7) * 8;       // dim offset
    const int vd   = tid >> 2;            // 0..63 (dim)
    const int vko  = (tid & 3) * 8;       // key offset

    const unsigned short* kp = kgb + (size_t)(ck * 512) * 64;   // tile stride 2048
    const unsigned short* vp = vgb + ck * 512;                  // tile stride 32

    // prologue: tile 0 -> buf 0
    s16x8 nk = *(const s16x8*)(kp + (size_t)krow * 64 + koff);
    s16x8 nv = *(const s16x8*)(vp + (size_t)vd * 4096 + vko);
    *(s16x8*)&kt[0][krow][koff] = nk;
    *(s16x8*)&vt[0][vd][vko]    = nv;
    __syncthreads();

    #pragma unroll 2
    for (int t = 0; t < 16; t++) {
        const int buf = t & 1;
        // issue next tile's global loads first: latency hides under compute
        if (t < 15) {
            nk = *(const s16x8*)(kp + (size_t)(t + 1) * 2048 + (size_t)krow * 64 + koff);
            nv = *(const s16x8*)(vp + (t + 1) * 32 + (size_t)vd * 4096 + vko);
        }

        // S = Q K^T for this 32-key tile; K frags feed both subtiles
        #pragma unroll
        for (int nt2 = 0; nt2 < 2; nt2++) {
            const int key = nt2 * 16 + l15;
            s16x8 k0 = *(const s16x8*)&kt[buf][key][quad * 8];
            s16x8 k1 = *(const s16x8*)&kt[buf][key][32 + quad * 8];
            #pragma unroll
            for (int sub = 0; sub < 2; sub++) {
                fx4 sc = (fx4){0.f, 0.f, 0.f, 0.f};
                __builtin_amdgcn_s_setprio(1);
                sc = __builtin_amdgcn_mfma_f32_16x16x32_bf16(qh[sub][0], k0, sc, 0, 0, 0);
                sc = __builtin_amdgcn_mfma_f32_16x16x32_bf16(ql[sub][0], k0, sc, 0, 0, 0);
                sc = __builtin_amdgcn_mfma_f32_16x16x32_bf16(qh[sub][1], k1, sc, 0, 0, 0);
                sc = __builtin_amdgcn_mfma_f32_16x16x32_bf16(ql[sub][1], k1, sc, 0, 0, 0);
                __builtin_amdgcn_s_setprio(0);
                // P = exp(S) -> bf16 -> wave-private LDS (C -> A layout)
                #pragma unroll
                for (int r = 0; r < 4; r++) {
                    float p = __builtin_amdgcn_exp2f(sc[r] * LOG2E);
                    unsigned short pb = f2bf(p);
                    lsum[sub][r] += bf2f(pb);   // denominator matches rounded numerator
                    pt[w][sub * 16 + quad * 4 + r][nt2 * 16 + l15] = pb;
                }
            }
        }
        // O += P V for this tile (k=32 exactly fills one MFMA per output tile)
        s16x8 pa0 = *(const s16x8*)&pt[w][l15][quad * 8];
        s16x8 pa1 = *(const s16x8*)&pt[w][16 + l15][quad * 8];
        __builtin_amdgcn_s_setprio(1);
        #pragma unroll
        for (int nt = 0; nt < 4; nt++) {
            s16x8 vf = *(const s16x8*)&vt[buf][nt * 16 + l15][quad * 8];
            accO[0][nt] = __builtin_amdgcn_mfma_f32_16x16x32_bf16(pa0, vf, accO[0][nt], 0, 0, 0);
            accO[1][nt] = __builtin_amdgcn_mfma_f32_16x16x32_bf16(pa1, vf, accO[1][nt], 0, 0, 0);
        }
        __builtin_amdgcn_s_setprio(0);

        // stage tile t+1 into the OTHER buffer (its readers finished before
        // the barrier at the end of iter t-1); overlaps with compute above
        if (t < 15) {
            *(s16x8*)&kt[buf ^ 1][krow][koff] = nk;
            *(s16x8*)&vt[buf ^ 1][vd][vko]    = nv;
        }
        __syncthreads();   // tile t+1 visible; tile t readers drained
    }

    // reduce row-sums across the 16 lanes sharing each row group
    #pragma unroll
    for (int sub = 0; sub < 2; sub++)
        #pragma unroll
        for (int r = 0; r < 4; r++) {
            float v = lsum[sub][r];
            #pragma unroll
            for (int o = 1; o < 16; o <<= 1) v += __shfl_xor(v, o);
            lsum[sub][r] = v;
        }
    // write partials: pOb[ck][b*4096+q][64] (bf16), pL[ck][b*4096+q] (fp32)
    #pragma unroll
    for (int sub = 0; sub < 2; sub++)
        #pragma unroll
        for (int r = 0; r < 4; r++) {
            int qrow = q0 + w * 32 + sub * 16 + quad * 4 + r;
            size_t grow = (size_t)b * 4096 + qrow;
            #pragma unroll
            for (int nt = 0; nt < 4; nt++)
                pOb[((size_t)ck * 16384 + grow) * 64 + nt * 16 + l15] = f2bf(accO[sub][nt][r]);
            if (l15 == 0)
                pL[(size_t)ck * 16384 + grow] = lsum[sub][r];
        }
}

// ---------------------------------------------------------------------------
// Kernel 4: combine partials: out = (sum_c pOb) * mask / (sum_c pL)  (unchanged)
// ---------------------------------------------------------------------------
__global__ __launch_bounds__(256) void combine_kernel(
    const unsigned short* __restrict__ pOb, const float* __restrict__ pL,
    const float* __restrict__ mask, float* __restrict__ out)
{
    int idx = blockIdx.x * 256 + threadIdx.x;   // 262144 = (b*4096+s)*16 + dgrp
    int q  = idx >> 4;
    int dg = idx & 15;
    fx4 s = (fx4){0.f, 0.f, 0.f, 0.f};
    float l = 0.f;
    #pragma unroll
    for (int c = 0; c < 8; c++) {
        u16x4 h = *(const u16x4*)(pOb + ((size_t)c * 16384 + q) * 64 + dg * 4);
        s.x += bf2f(h.x);
        s.y += bf2f(h.y);
        s.z += bf2f(h.z);
        s.w += bf2f(h.w);
        l += pL[(size_t)c * 16384 + q];
    }
    float scale = mask[q] / l;
    *(fx4*)(out + (size_t)q * 64 + dg * 4) = s * scale;
}

// ---------------------------------------------------------------------------
extern "C" void kernel_launch(void* const* d_in, const int* in_sizes, int n_in,
                              void* d_out, int out_size, void* d_ws, size_t ws_size,
                              hipStream_t stream)
{
    const float* X    = (const float*)d_in[0];
    const float* mask = (const float*)d_in[1];
    const float* Wq   = (const float*)d_in[2];
    const float* bq   = (const float*)d_in[3];
    const float* Wk   = (const float*)d_in[4];
    const float* bk   = (const float*)d_in[5];
    const float* Wv   = (const float*)d_in[6];
    const float* bv   = (const float*)d_in[7];
    float* out = (float*)d_out;

    char* ws = (char*)d_ws;
    unsigned short* q_hi  = (unsigned short*)(ws);                       // 2 MB
    unsigned short* q_lo  = (unsigned short*)(ws + (size_t)(2u << 20));  // 2 MB
    unsigned short* k_bf  = (unsigned short*)(ws + (size_t)(4u << 20));  // 2 MB
    unsigned short* vt_g  = (unsigned short*)(ws + (size_t)(6u << 20));  // 2 MB  [b][d][s]
    unsigned short* wt_hi = (unsigned short*)(ws + (size_t)(8u << 20));  // 384 KB
    unsigned short* wt_lo = (unsigned short*)(ws + (size_t)(8u << 20) + 393216);
    unsigned short* pOb   = (unsigned short*)(ws + (size_t)(9u << 20));  // 16 MB [8][16384][64] bf16
    float*          pL    = (float*)(ws + (size_t)(25u << 20));          // 512 KB [8][16384]

    hipLaunchKernelGGL(prep_w_kernel, dim3(3, 16), dim3(256), 0, stream,
                       Wq, Wk, Wv, wt_hi, wt_lo);
    hipLaunchKernelGGL(proj_kernel, dim3(256), dim3(768), 0, stream,
                       X, wt_hi, wt_lo, bq, bk, bv, q_hi, q_lo, k_bf, vt_g);
    hipLaunchKernelGGL(attn_kernel, dim3(32, 8, 4), dim3(256), 0, stream,
                       q_hi, q_lo, k_bf, vt_g, pOb, pL);
    hipLaunchKernelGGL(combine_kernel, dim3(1024), dim3(256), 0, stream,
                       pOb, pL, mask, out);
}

// Round 8
// 162.389 us; speedup vs baseline: 1.3802x; 1.3802x over previous
//
#include <hip/hip_runtime.h>

// B=4, S=4096, D_IN=1024, D_QK=D_V=64
// out = softmax(relu(XWq+bq) @ relu(XWk+bk)^T) @ relu(XWv+bv) * mask

typedef short s16x8 __attribute__((ext_vector_type(8)));   // 8 bf16 (4 VGPRs) MFMA frag
typedef float fx4   __attribute__((ext_vector_type(4)));   // MFMA accum frag
typedef unsigned short u16x4 __attribute__((ext_vector_type(4)));

#define LOG2E 1.4426950408889634f

__device__ __forceinline__ unsigned short f2bf(float x) {   // fp32 -> bf16 RTN
    unsigned int u = __float_as_uint(x);
    u += 0x7FFFu + ((u >> 16) & 1u);
    return (unsigned short)(u >> 16);
}
__device__ __forceinline__ float bf2f(unsigned short b) {
    return __uint_as_float(((unsigned int)b) << 16);
}

// ---------------------------------------------------------------------------
// Kernel 1: split W{q,k,v} [1024][64] fp32 into W^T hi/lo bf16 [3][64][1024].
// (unchanged)
// ---------------------------------------------------------------------------
__global__ __launch_bounds__(256) void prep_w_kernel(
    const float* __restrict__ Wq, const float* __restrict__ Wk, const float* __restrict__ Wv,
    unsigned short* __restrict__ wt_hi, unsigned short* __restrict__ wt_lo)
{
    __shared__ __align__(16) unsigned short sh[64][72];   // [c][k_local]
    __shared__ __align__(16) unsigned short sl[64][72];

    const int y  = blockIdx.x;
    const int kt = blockIdx.y;
    const float* W = (y == 0) ? Wq : (y == 1) ? Wk : Wv;
    const int t  = threadIdx.x;

    const int kl = t >> 2;
    const int c0 = (t & 3) * 16;
    const float* src = W + (size_t)(kt * 64 + kl) * 64 + c0;
    #pragma unroll
    for (int j = 0; j < 4; j++) {
        fx4 v = *(const fx4*)(src + j * 4);
        #pragma unroll
        for (int i = 0; i < 4; i++) {
            float x = v[i];
            unsigned short h = f2bf(x);
            unsigned short l = f2bf(x - bf2f(h));
            sh[c0 + j * 4 + i][kl] = h;
            sl[c0 + j * 4 + i][kl] = l;
        }
    }
    __syncthreads();

    const int c  = t >> 2;
    const int k0 = (t & 3) * 16;
    size_t o = (size_t)(y * 64 + c) * 1024 + kt * 64 + k0;
    *(s16x8*)(wt_hi + o)     = *(const s16x8*)&sh[c][k0];
    *(s16x8*)(wt_hi + o + 8) = *(const s16x8*)&sh[c][k0 + 8];
    *(s16x8*)(wt_lo + o)     = *(const s16x8*)&sl[c][k0];
    *(s16x8*)(wt_lo + o + 8) = *(const s16x8*)&sl[c][k0 + 8];
}

// ---------------------------------------------------------------------------
// Kernel 2 (v6): FUSED q/k/v projection, B in LDS. Grid 256, block 768 =
// 12 waves = 2 row-groups x 6 col-groups ({q,k,v} x 2 col-halves). X
// converted once per m-tile; W relayed global->reg(depth 2)->LDS, X depth 4.
// (unchanged -- measured <41.6us)
// ---------------------------------------------------------------------------
__global__ __launch_bounds__(768, 3) void proj_kernel(
    const float* __restrict__ X,
    const unsigned short* __restrict__ wt_hi, const unsigned short* __restrict__ wt_lo,
    const float* __restrict__ bq, const float* __restrict__ bk, const float* __restrict__ bv,
    unsigned short* __restrict__ q_hi, unsigned short* __restrict__ q_lo,
    unsigned short* __restrict__ k_bf, unsigned short* __restrict__ vt_g)
{
    __shared__ __align__(16) unsigned short a_hi[64][72];    // X tile hi (+8 pad)
    __shared__ __align__(16) unsigned short a_lo[64][72];    // X tile lo
    __shared__ __align__(16) unsigned short bsh[192][72];    // W^T all-y hi [col][k]
    __shared__ __align__(16) unsigned short bsl[192][72];    // W^T all-y lo

    const int tid  = threadIdx.x;
    const int lane = tid & 63;
    const int w    = tid >> 6;      // 0..11
    const int quad = lane >> 4;
    const int l15  = lane & 15;
    const int rowg = w & 1;         // 32-row group
    const int colg = w >> 1;        // 0..5 = {q,k,v} x {col half}
    const int y    = colg >> 1;     // 0=q 1=k 2=v
    const int ch   = colg & 1;      // 32-col half within y

    const int m0 = blockIdx.x * 64;

    fx4 acc[2][2];                  // [sub 16 rows][nt 16 cols]
    #pragma unroll
    for (int i = 0; i < 2; i++)
        #pragma unroll
        for (int j = 0; j < 2; j++) acc[i][j] = (fx4){0.f, 0.f, 0.f, 0.f};

    // X staging: threads 0..511, 8 floats each (rows xrow, xrow+32)
    const int xrow = tid >> 4;        // 0..31 (tid<512)
    const int xoff = (tid & 15) * 4;
    const float* xb0 = X + (size_t)(m0 + xrow) * 1024 + xoff;
    const float* xb1 = X + (size_t)(m0 + xrow + 32) * 1024 + xoff;

    // W staging: all 768 threads, 32 B (hi) + 32 B (lo) each per kc
    const int wrow = tid >> 2;        // 0..191
    const int wk   = (tid & 3) * 16;  // k-offset (shorts)
    const size_t wb = (size_t)wrow * 1024 + wk;

    // register relays: X depth 4, W depth 2 (v2-proven pattern)
    fx4   xr[4][2];
    s16x8 wrh[2][2], wrl[2][2];
    if (tid < 512) {
        #pragma unroll
        for (int d = 0; d < 4; d++) {
            xr[d][0] = *(const fx4*)(xb0 + d * 64);
            xr[d][1] = *(const fx4*)(xb1 + d * 64);
        }
    }
    #pragma unroll
    for (int d = 0; d < 2; d++) {
        wrh[d][0] = *(const s16x8*)(wt_hi + wb + d * 64);
        wrh[d][1] = *(const s16x8*)(wt_hi + wb + d * 64 + 8);
        wrl[d][0] = *(const s16x8*)(wt_lo + wb + d * 64);
        wrl[d][1] = *(const s16x8*)(wt_lo + wb + d * 64 + 8);
    }

    #pragma unroll 4
    for (int kc = 0; kc < 16; kc++) {
        if (kc) __syncthreads();   // prev iter's LDS readers done
        if (tid < 512) {
            #pragma unroll
            for (int i = 0; i < 2; i++) {
                fx4 xv = xr[kc & 3][i];
                unsigned short h0 = f2bf(xv.x), h1 = f2bf(xv.y), h2 = f2bf(xv.z), h3 = f2bf(xv.w);
                unsigned short l0 = f2bf(xv.x - bf2f(h0)), l1 = f2bf(xv.y - bf2f(h1));
                unsigned short l2 = f2bf(xv.z - bf2f(h2)), l3 = f2bf(xv.w - bf2f(h3));
                *(u16x4*)&a_hi[xrow + i * 32][xoff] = (u16x4){h0, h1, h2, h3};
                *(u16x4*)&a_lo[xrow + i * 32][xoff] = (u16x4){l0, l1, l2, l3};
            }
        }
        *(s16x8*)&bsh[wrow][wk]     = wrh[kc & 1][0];
        *(s16x8*)&bsh[wrow][wk + 8] = wrh[kc & 1][1];
        *(s16x8*)&bsl[wrow][wk]     = wrl[kc & 1][0];
        *(s16x8*)&bsl[wrow][wk + 8] = wrl[kc & 1][1];
        __syncthreads();

        // refill relays (latency hides behind this iter's frag reads + MFMAs)
        if (tid < 512 && kc < 12) {
            xr[kc & 3][0] = *(const fx4*)(xb0 + (kc + 4) * 64);
            xr[kc & 3][1] = *(const fx4*)(xb1 + (kc + 4) * 64);
        }
        if (kc < 14) {
            wrh[kc & 1][0] = *(const s16x8*)(wt_hi + wb + (kc + 2) * 64);
            wrh[kc & 1][1] = *(const s16x8*)(wt_hi + wb + (kc + 2) * 64 + 8);
            wrl[kc & 1][0] = *(const s16x8*)(wt_lo + wb + (kc + 2) * 64);
            wrl[kc & 1][1] = *(const s16x8*)(wt_lo + wb + (kc + 2) * 64 + 8);
        }

        // A frags (32 rows: sub=0,1)
        s16x8 ah[2][2], al[2][2];
        #pragma unroll
        for (int sub = 0; sub < 2; sub++)
            #pragma unroll
            for (int ks = 0; ks < 2; ks++) {
                const int r = rowg * 32 + sub * 16 + l15;
                ah[sub][ks] = *(const s16x8*)&a_hi[r][ks * 32 + quad * 8];
                al[sub][ks] = *(const s16x8*)&a_lo[r][ks * 32 + quad * 8];
            }
        #pragma unroll
        for (int nt = 0; nt < 2; nt++) {
            const int br = colg * 32 + nt * 16 + l15;
            #pragma unroll
            for (int ks = 0; ks < 2; ks++) {
                s16x8 bh = *(const s16x8*)&bsh[br][ks * 32 + quad * 8];
                s16x8 bl = *(const s16x8*)&bsl[br][ks * 32 + quad * 8];
                #pragma unroll
                for (int sub = 0; sub < 2; sub++) {
                    acc[sub][nt] = __builtin_amdgcn_mfma_f32_16x16x32_bf16(ah[sub][ks], bh, acc[sub][nt], 0, 0, 0);
                    acc[sub][nt] = __builtin_amdgcn_mfma_f32_16x16x32_bf16(ah[sub][ks], bl, acc[sub][nt], 0, 0, 0);
                    acc[sub][nt] = __builtin_amdgcn_mfma_f32_16x16x32_bf16(al[sub][ks], bh, acc[sub][nt], 0, 0, 0);
                }
            }
        }
    }
    __syncthreads();   // all MFMA LDS reads done before vtr alias writes

    // epilogue: bias + relu; q -> hi/lo, k -> bf16, v -> transpose via LDS
    const float* bias = (y == 0) ? bq : (y == 1) ? bk : bv;
    const int b   = m0 >> 12;
    const int s0b = m0 & 4095;
    unsigned short* vtr = &a_hi[0][0];  // alias: [64 d][72]

    #pragma unroll
    for (int sub = 0; sub < 2; sub++)
        #pragma unroll
        for (int nt = 0; nt < 2; nt++) {
            const int col = ch * 32 + nt * 16 + l15;
            const float bb = bias[col];
            const int rloc = rowg * 32 + sub * 16 + quad * 4;
            #pragma unroll
            for (int r = 0; r < 4; r++) {
                float v = fmaxf(acc[sub][nt][r] + bb, 0.f);
                size_t grow = (size_t)(m0 + rloc + r);
                if (y == 0) {
                    unsigned short h = f2bf(v);
                    unsigned short l = f2bf(v - bf2f(h));
                    q_hi[grow * 64 + col] = h;
                    q_lo[grow * 64 + col] = l;
                } else if (y == 1) {
                    k_bf[grow * 64 + col] = f2bf(v);
                } else {
                    vtr[col * 72 + rloc + r] = f2bf(v);  // transpose via LDS
                }
            }
        }
    __syncthreads();   // v-waves' vtr writes visible to storing threads
    if (tid < 512) {
        int row = tid >> 3;          // d 0..63
        int off = (tid & 7) * 8;     // s chunk
        s16x8 vv = *(const s16x8*)&vtr[row * 72 + off];
        *(s16x8*)(vt_g + (size_t)(b * 64 + row) * 4096 + s0b + off) = vv;
    }
}

// ---------------------------------------------------------------------------
// Kernel 3 (v9): fused attention. v8 failed via FETCH explosion (18->190MB:
// KVBLK=32 half-line V reads + fast tile turnover thrashed L2). v9 keeps
// v7's proven serialization structure (stage -> barrier -> compute ->
// barrier, T14 reg prefetch, setprio) but goes BIGGER: KVBLK=128 (4 super-
// tiles per 512-key chunk -> barriers 16->8) and 512-thread blocks owning
// 256 q-rows (8 waves x 32q, grid 16x8x4=512 = exactly 2 blocks/CU, no
// tail; K/V staging per q-row halved). V^T rows staged 256B contiguous
// (full lines). Key order and per-output MFMA/exp/add order IDENTICAL to
// v7 => bit-identical. LDS 56.3KB (kt[128][72] + vt[64][136] + pt[8][32]
// [40], all 16B-aligned row strides); launch_bounds(512,2) -> VGPR cap 128.
// ---------------------------------------------------------------------------
__global__ __launch_bounds__(512, 2) void attn_kernel(
    const unsigned short* __restrict__ q_hi, const unsigned short* __restrict__ q_lo,
    const unsigned short* __restrict__ k_bf, const unsigned short* __restrict__ vt_g,
    unsigned short* __restrict__ pOb, float* __restrict__ pL)
{
    __shared__ __align__(16) unsigned short kt[128][72];     // [key][dim]
    __shared__ __align__(16) unsigned short vt[64][136];     // [dim][key]  (V^T)
    __shared__ __align__(16) unsigned short pt[8][32][40];   // per-wave P [q][key]

    const int tid  = threadIdx.x;
    const int lane = tid & 63;
    const int w    = tid >> 6;           // 0..7
    const int quad = lane >> 4;
    const int l15  = lane & 15;
    const int ck   = blockIdx.y;         // key chunk (512 keys = 4 tiles x 128)
    const int b    = blockIdx.z;
    const int q0   = blockIdx.x * 256;   // within batch

    // Q fragments for both 16-row subtiles (A layout: m=lane&15, k=quad*8+j)
    const size_t qbase = ((size_t)b * 4096 + q0 + w * 32 + l15) * 64 + quad * 8;
    s16x8 qh[2][2], ql[2][2];            // [sub][k-half]
    #pragma unroll
    for (int sub = 0; sub < 2; sub++) {
        qh[sub][0] = *(const s16x8*)(q_hi + qbase + sub * 1024);
        qh[sub][1] = *(const s16x8*)(q_hi + qbase + sub * 1024 + 32);
        ql[sub][0] = *(const s16x8*)(q_lo + qbase + sub * 1024);
        ql[sub][1] = *(const s16x8*)(q_lo + qbase + sub * 1024 + 32);
    }

    fx4 accO[2][4];
    #pragma unroll
    for (int sub = 0; sub < 2; sub++)
        #pragma unroll
        for (int nt = 0; nt < 4; nt++) accO[sub][nt] = (fx4){0.f, 0.f, 0.f, 0.f};
    float lsum[2][4] = {{0.f, 0.f, 0.f, 0.f}, {0.f, 0.f, 0.f, 0.f}};

    const unsigned short* kgb = k_bf + (size_t)b * 4096 * 64;  // [s][64]
    const unsigned short* vgb = vt_g + (size_t)b * 64 * 4096;  // [d][s]

    // staging: 512 threads; K: rows srow, srow+64 (full 128B rows);
    // V^T: dim srow, key chunks koff, koff+64 (256B contiguous per row/tile)
    const int srow = tid >> 3;            // 0..63
    const int koff = (tid & 7) * 8;       // 16B chunk offset

    const unsigned short* kp = kgb + (size_t)(ck * 512) * 64;   // tile stride 8192
    const unsigned short* vp = vgb + ck * 512;                  // tile stride 128

    // prologue prefetch of super-tile 0 into registers
    s16x8 nk0 = *(const s16x8*)(kp + (size_t)srow * 64 + koff);
    s16x8 nk1 = *(const s16x8*)(kp + (size_t)(srow + 64) * 64 + koff);
    s16x8 nv0 = *(const s16x8*)(vp + (size_t)srow * 4096 + koff);
    s16x8 nv1 = *(const s16x8*)(vp + (size_t)srow * 4096 + koff + 64);

    for (int t = 0; t < 4; t++) {
        // regs -> LDS (prev iter's trailing barrier guarantees readers done)
        *(s16x8*)&kt[srow][koff]      = nk0;
        *(s16x8*)&kt[srow + 64][koff] = nk1;
        *(s16x8*)&vt[srow][koff]      = nv0;
        *(s16x8*)&vt[srow][koff + 64] = nv1;
        __syncthreads();
        // issue next super-tile's loads; latency hides under compute below
        if (t < 3) {
            nk0 = *(const s16x8*)(kp + (size_t)(t + 1) * 8192 + (size_t)srow * 64 + koff);
            nk1 = *(const s16x8*)(kp + (size_t)(t + 1) * 8192 + (size_t)(srow + 64) * 64 + koff);
            nv0 = *(const s16x8*)(vp + (t + 1) * 128 + (size_t)srow * 4096 + koff);
            nv1 = *(const s16x8*)(vp + (t + 1) * 128 + (size_t)srow * 4096 + koff + 64);
        }

        #pragma unroll
        for (int h = 0; h < 2; h++) {
            #pragma unroll
            for (int kh = 0; kh < 2; kh++) {
                // S = Q K^T for this 32-key group; K frags feed both subtiles
                #pragma unroll
                for (int nt2 = 0; nt2 < 2; nt2++) {
                    const int key = h * 64 + kh * 32 + nt2 * 16 + l15;
                    s16x8 k0 = *(const s16x8*)&kt[key][quad * 8];
                    s16x8 k1 = *(const s16x8*)&kt[key][32 + quad * 8];
                    #pragma unroll
                    for (int sub = 0; sub < 2; sub++) {
                        fx4 sc = (fx4){0.f, 0.f, 0.f, 0.f};
                        __builtin_amdgcn_s_setprio(1);
                        sc = __builtin_amdgcn_mfma_f32_16x16x32_bf16(qh[sub][0], k0, sc, 0, 0, 0);
                        sc = __builtin_amdgcn_mfma_f32_16x16x32_bf16(ql[sub][0], k0, sc, 0, 0, 0);
                        sc = __builtin_amdgcn_mfma_f32_16x16x32_bf16(qh[sub][1], k1, sc, 0, 0, 0);
                        sc = __builtin_amdgcn_mfma_f32_16x16x32_bf16(ql[sub][1], k1, sc, 0, 0, 0);
                        __builtin_amdgcn_s_setprio(0);
                        // P = exp(S) -> bf16 -> wave-private LDS (C -> A layout)
                        #pragma unroll
                        for (int r = 0; r < 4; r++) {
                            float p = __builtin_amdgcn_exp2f(sc[r] * LOG2E);
                            unsigned short pb = f2bf(p);
                            lsum[sub][r] += bf2f(pb);   // denominator matches rounded numerator
                            pt[w][sub * 16 + quad * 4 + r][nt2 * 16 + l15] = pb;
                        }
                    }
                }
                // O += P V for this 32-key group; V frags feed both subtiles
                s16x8 pa0 = *(const s16x8*)&pt[w][l15][quad * 8];
                s16x8 pa1 = *(const s16x8*)&pt[w][16 + l15][quad * 8];
                __builtin_amdgcn_s_setprio(1);
                #pragma unroll
                for (int nt = 0; nt < 4; nt++) {
                    s16x8 vf = *(const s16x8*)&vt[nt * 16 + l15][h * 64 + kh * 32 + quad * 8];
                    accO[0][nt] = __builtin_amdgcn_mfma_f32_16x16x32_bf16(pa0, vf, accO[0][nt], 0, 0, 0);
                    accO[1][nt] = __builtin_amdgcn_mfma_f32_16x16x32_bf16(pa1, vf, accO[1][nt], 0, 0, 0);
                }
                __builtin_amdgcn_s_setprio(0);
            }
        }
        __syncthreads();   // this super-tile's readers drained before restage
    }

    // reduce row-sums across the 16 lanes sharing each row group
    #pragma unroll
    for (int sub = 0; sub < 2; sub++)
        #pragma unroll
        for (int r = 0; r < 4; r++) {
            float v = lsum[sub][r];
            #pragma unroll
            for (int o = 1; o < 16; o <<= 1) v += __shfl_xor(v, o);
            lsum[sub][r] = v;
        }
    // write partials: pOb[ck][b*4096+q][64] (bf16), pL[ck][b*4096+q] (fp32)
    #pragma unroll
    for (int sub = 0; sub < 2; sub++)
        #pragma unroll
        for (int r = 0; r < 4; r++) {
            int qrow = q0 + w * 32 + sub * 16 + quad * 4 + r;
            size_t grow = (size_t)b * 4096 + qrow;
            #pragma unroll
            for (int nt = 0; nt < 4; nt++)
                pOb[((size_t)ck * 16384 + grow) * 64 + nt * 16 + l15] = f2bf(accO[sub][nt][r]);
            if (l15 == 0)
                pL[(size_t)ck * 16384 + grow] = lsum[sub][r];
        }
}

// ---------------------------------------------------------------------------
// Kernel 4: combine partials: out = (sum_c pOb) * mask / (sum_c pL)  (unchanged)
// ---------------------------------------------------------------------------
__global__ __launch_bounds__(256) void combine_kernel(
    const unsigned short* __restrict__ pOb, const float* __restrict__ pL,
    const float* __restrict__ mask, float* __restrict__ out)
{
    int idx = blockIdx.x * 256 + threadIdx.x;   // 262144 = (b*4096+s)*16 + dgrp
    int q  = idx >> 4;
    int dg = idx & 15;
    fx4 s = (fx4){0.f, 0.f, 0.f, 0.f};
    float l = 0.f;
    #pragma unroll
    for (int c = 0; c < 8; c++) {
        u16x4 h = *(const u16x4*)(pOb + ((size_t)c * 16384 + q) * 64 + dg * 4);
        s.x += bf2f(h.x);
        s.y += bf2f(h.y);
        s.z += bf2f(h.z);
        s.w += bf2f(h.w);
        l += pL[(size_t)c * 16384 + q];
    }
    float scale = mask[q] / l;
    *(fx4*)(out + (size_t)q * 64 + dg * 4) = s * scale;
}

// ---------------------------------------------------------------------------
extern "C" void kernel_launch(void* const* d_in, const int* in_sizes, int n_in,
                              void* d_out, int out_size, void* d_ws, size_t ws_size,
                              hipStream_t stream)
{
    const float* X    = (const float*)d_in[0];
    const float* mask = (const float*)d_in[1];
    const float* Wq   = (const float*)d_in[2];
    const float* bq   = (const float*)d_in[3];
    const float* Wk   = (const float*)d_in[4];
    const float* bk   = (const float*)d_in[5];
    const float* Wv   = (const float*)d_in[6];
    const float* bv   = (const float*)d_in[7];
    float* out = (float*)d_out;

    char* ws = (char*)d_ws;
    unsigned short* q_hi  = (unsigned short*)(ws);                       // 2 MB
    unsigned short* q_lo  = (unsigned short*)(ws + (size_t)(2u << 20));  // 2 MB
    unsigned short* k_bf  = (unsigned short*)(ws + (size_t)(4u << 20));  // 2 MB
    unsigned short* vt_g  = (unsigned short*)(ws + (size_t)(6u << 20));  // 2 MB  [b][d][s]
    unsigned short* wt_hi = (unsigned short*)(ws + (size_t)(8u << 20));  // 384 KB
    unsigned short* wt_lo = (unsigned short*)(ws + (size_t)(8u << 20) + 393216);
    unsigned short* pOb   = (unsigned short*)(ws + (size_t)(9u << 20));  // 16 MB [8][16384][64] bf16
    float*          pL    = (float*)(ws + (size_t)(25u << 20));          // 512 KB [8][16384]

    hipLaunchKernelGGL(prep_w_kernel, dim3(3, 16), dim3(256), 0, stream,
                       Wq, Wk, Wv, wt_hi, wt_lo);
    hipLaunchKernelGGL(proj_kernel, dim3(256), dim3(768), 0, stream,
                       X, wt_hi, wt_lo, bq, bk, bv, q_hi, q_lo, k_bf, vt_g);
    hipLaunchKernelGGL(attn_kernel, dim3(16, 8, 4), dim3(512), 0, stream,
                       q_hi, q_lo, k_bf, vt_g, pOb, pL);
    hipLaunchKernelGGL(combine_kernel, dim3(1024), dim3(256), 0, stream,
                       pOb, pL, mask, out);
}

// Round 11
// 160.856 us; speedup vs baseline: 1.3934x; 1.0095x over previous
//
#include <hip/hip_runtime.h>

// B=4, S=4096, D_IN=1024, D_QK=D_V=64
// out = softmax(relu(XWq+bq) @ relu(XWk+bk)^T) @ relu(XWv+bv) * mask

typedef short s16x8 __attribute__((ext_vector_type(8)));   // 8 bf16 (4 VGPRs) MFMA frag
typedef float fx4   __attribute__((ext_vector_type(4)));   // MFMA accum frag
typedef unsigned short u16x4 __attribute__((ext_vector_type(4)));

#define LOG2E 1.4426950408889634f

__device__ __forceinline__ unsigned short f2bf(float x) {   // fp32 -> bf16 RTN
    unsigned int u = __float_as_uint(x);
    u += 0x7FFFu + ((u >> 16) & 1u);
    return (unsigned short)(u >> 16);
}
__device__ __forceinline__ float bf2f(unsigned short b) {
    return __uint_as_float(((unsigned int)b) << 16);
}

// ---------------------------------------------------------------------------
// Kernel 1: split W{q,k,v} [1024][64] fp32 into W^T hi/lo bf16 [3][64][1024].
// (unchanged)
// ---------------------------------------------------------------------------
__global__ __launch_bounds__(256) void prep_w_kernel(
    const float* __restrict__ Wq, const float* __restrict__ Wk, const float* __restrict__ Wv,
    unsigned short* __restrict__ wt_hi, unsigned short* __restrict__ wt_lo)
{
    __shared__ __align__(16) unsigned short sh[64][72];   // [c][k_local]
    __shared__ __align__(16) unsigned short sl[64][72];

    const int y  = blockIdx.x;
    const int kt = blockIdx.y;
    const float* W = (y == 0) ? Wq : (y == 1) ? Wk : Wv;
    const int t  = threadIdx.x;

    const int kl = t >> 2;
    const int c0 = (t & 3) * 16;
    const float* src = W + (size_t)(kt * 64 + kl) * 64 + c0;
    #pragma unroll
    for (int j = 0; j < 4; j++) {
        fx4 v = *(const fx4*)(src + j * 4);
        #pragma unroll
        for (int i = 0; i < 4; i++) {
            float x = v[i];
            unsigned short h = f2bf(x);
            unsigned short l = f2bf(x - bf2f(h));
            sh[c0 + j * 4 + i][kl] = h;
            sl[c0 + j * 4 + i][kl] = l;
        }
    }
    __syncthreads();

    const int c  = t >> 2;
    const int k0 = (t & 3) * 16;
    size_t o = (size_t)(y * 64 + c) * 1024 + kt * 64 + k0;
    *(s16x8*)(wt_hi + o)     = *(const s16x8*)&sh[c][k0];
    *(s16x8*)(wt_hi + o + 8) = *(const s16x8*)&sh[c][k0 + 8];
    *(s16x8*)(wt_lo + o)     = *(const s16x8*)&sl[c][k0];
    *(s16x8*)(wt_lo + o + 8) = *(const s16x8*)&sl[c][k0 + 8];
}

// ---------------------------------------------------------------------------
// Kernel 2 (v10b): FUSED q/k/v projection, B in LDS, BK=128 PHASES.
// Same phase structure as v10 (stage TWO k-chunks per phase, compute both
// back-to-back, barriers 31->15; register relays = v2/v6-proven pattern).
// v10b delta: UNPADDED LDS rows (64 shorts = 128B) with a 16B-chunk XOR
// swizzle, chunk ^= (row & 7) -- T2's pattern. This (a) cuts LDS from
// 147,456 to exactly 131,072 B (the gfx950-proven 128KiB class; v10's
// >128KiB static alloc was the one unusual feature in two container
// failures), and (b) is bank-uniform: bank = (swzchunk*4+w)%32 with the
// row term dropping out, XOR spreads 64 lanes over all 32 banks evenly
// for both frag reads and staging writes. Same values at swizzled
// addresses => bit-identical results.
// ---------------------------------------------------------------------------
__global__ __launch_bounds__(768, 3) void proj_kernel(
    const float* __restrict__ X,
    const unsigned short* __restrict__ wt_hi, const unsigned short* __restrict__ wt_lo,
    const float* __restrict__ bq, const float* __restrict__ bk, const float* __restrict__ bv,
    unsigned short* __restrict__ q_hi, unsigned short* __restrict__ q_lo,
    unsigned short* __restrict__ k_bf, unsigned short* __restrict__ vt_g)
{
    __shared__ __align__(16) unsigned short a_hi[2][64][64];   // [kc-slot][row][k] swz
    __shared__ __align__(16) unsigned short a_lo[2][64][64];
    __shared__ __align__(16) unsigned short bsh[2][192][64];   // [kc-slot][col][k] swz
    __shared__ __align__(16) unsigned short bsl[2][192][64];

    const int tid  = threadIdx.x;
    const int lane = tid & 63;
    const int w    = tid >> 6;      // 0..11
    const int quad = lane >> 4;
    const int l15  = lane & 15;
    const int rowg = w & 1;         // 32-row group
    const int colg = w >> 1;        // 0..5 = {q,k,v} x {col half}
    const int y    = colg >> 1;     // 0=q 1=k 2=v
    const int ch   = colg & 1;      // 32-col half within y

    const int m0 = blockIdx.x * 64;

    fx4 acc[2][2];                  // [sub 16 rows][nt 16 cols]
    #pragma unroll
    for (int i = 0; i < 2; i++)
        #pragma unroll
        for (int j = 0; j < 2; j++) acc[i][j] = (fx4){0.f, 0.f, 0.f, 0.f};

    // X staging: threads 0..511, 8 floats each (rows xrow, xrow+32)
    const int xrow = tid >> 4;        // 0..31 (tid<512)
    const int xoff = (tid & 15) * 4;  // logical col (0,4,...,60)
    const float* xb0 = X + (size_t)(m0 + xrow) * 1024 + xoff;
    const float* xb1 = X + (size_t)(m0 + xrow + 32) * 1024 + xoff;

    // W staging: all 768 threads, 32 B (hi) + 32 B (lo) each per kc
    const int wrow = tid >> 2;        // 0..191
    const int wk   = (tid & 3) * 16;  // logical k-offset (0,16,32,48)
    const size_t wb = (size_t)wrow * 1024 + wk;
    // swizzled physical chunk offsets (shorts) for the two 16B halves
    const int wsw0 = (((wk >> 3)     ^ (wrow & 7)) << 3);
    const int wsw1 = ((((wk >> 3) + 1) ^ (wrow & 7)) << 3);

    // register relays: X depth 4 kc, W depth 2 kc (v2/v6-proven pattern)
    fx4   xr[4][2];
    s16x8 wrh[2][2], wrl[2][2];
    if (tid < 512) {
        #pragma unroll
        for (int d = 0; d < 4; d++) {
            xr[d][0] = *(const fx4*)(xb0 + d * 64);
            xr[d][1] = *(const fx4*)(xb1 + d * 64);
        }
    }
    #pragma unroll
    for (int d = 0; d < 2; d++) {
        wrh[d][0] = *(const s16x8*)(wt_hi + wb + d * 64);
        wrh[d][1] = *(const s16x8*)(wt_hi + wb + d * 64 + 8);
        wrl[d][0] = *(const s16x8*)(wt_lo + wb + d * 64);
        wrl[d][1] = *(const s16x8*)(wt_lo + wb + d * 64 + 8);
    }

    #pragma unroll 2
    for (int ph = 0; ph < 8; ph++) {
        if (ph) __syncthreads();   // prev phase's LDS readers done
        // stage kc = 2ph (slot 0) and kc = 2ph+1 (slot 1)
        #pragma unroll
        for (int half = 0; half < 2; half++) {
            const int kc = 2 * ph + half;
            if (tid < 512) {
                #pragma unroll
                for (int i = 0; i < 2; i++) {
                    fx4 xv = xr[kc & 3][i];
                    unsigned short h0 = f2bf(xv.x), h1 = f2bf(xv.y), h2 = f2bf(xv.z), h3 = f2bf(xv.w);
                    unsigned short l0 = f2bf(xv.x - bf2f(h0)), l1 = f2bf(xv.y - bf2f(h1));
                    unsigned short l2 = f2bf(xv.z - bf2f(h2)), l3 = f2bf(xv.w - bf2f(h3));
                    const int row = xrow + i * 32;
                    const int sw  = ((((xoff >> 3) ^ (row & 7)) << 3) | (xoff & 7));
                    *(u16x4*)&a_hi[half][row][sw] = (u16x4){h0, h1, h2, h3};
                    *(u16x4*)&a_lo[half][row][sw] = (u16x4){l0, l1, l2, l3};
                }
            }
            *(s16x8*)&bsh[half][wrow][wsw0] = wrh[half][0];
            *(s16x8*)&bsh[half][wrow][wsw1] = wrh[half][1];
            *(s16x8*)&bsl[half][wrow][wsw0] = wrl[half][0];
            *(s16x8*)&bsl[half][wrow][wsw1] = wrl[half][1];
        }
        __syncthreads();

        // refill relays (consumed >= 1 full phase later: latency covered)
        if (tid < 512 && ph < 6) {
            #pragma unroll
            for (int half = 0; half < 2; half++) {
                const int kc = 2 * ph + 4 + half;      // slots (2ph)&3, (2ph+1)&3
                xr[kc & 3][0] = *(const fx4*)(xb0 + kc * 64);
                xr[kc & 3][1] = *(const fx4*)(xb1 + kc * 64);
            }
        }
        if (ph < 7) {
            #pragma unroll
            for (int half = 0; half < 2; half++) {
                const int kc = 2 * ph + 2 + half;      // slots 0, 1
                wrh[half][0] = *(const s16x8*)(wt_hi + wb + kc * 64);
                wrh[half][1] = *(const s16x8*)(wt_hi + wb + kc * 64 + 8);
                wrl[half][0] = *(const s16x8*)(wt_lo + wb + kc * 64);
                wrl[half][1] = *(const s16x8*)(wt_lo + wb + kc * 64 + 8);
            }
        }

        // compute both k-chunks sequentially (same kc order as v6 => bit-identical)
        #pragma unroll
        for (int half = 0; half < 2; half++) {
            const int r = rowg * 32 + ( /*sub*/ 0) * 16 + l15;   // per-sub below
            s16x8 ah[2][2], al[2][2];
            #pragma unroll
            for (int sub = 0; sub < 2; sub++)
                #pragma unroll
                for (int ks = 0; ks < 2; ks++) {
                    const int rr = rowg * 32 + sub * 16 + l15;
                    const int sw = (((ks * 4 + quad) ^ (rr & 7)) << 3);
                    ah[sub][ks] = *(const s16x8*)&a_hi[half][rr][sw];
                    al[sub][ks] = *(const s16x8*)&a_lo[half][rr][sw];
                }
            (void)r;
            #pragma unroll
            for (int nt = 0; nt < 2; nt++) {
                const int br = colg * 32 + nt * 16 + l15;
                #pragma unroll
                for (int ks = 0; ks < 2; ks++) {
                    const int sw = (((ks * 4 + quad) ^ (br & 7)) << 3);
                    s16x8 bh = *(const s16x8*)&bsh[half][br][sw];
                    s16x8 bl = *(const s16x8*)&bsl[half][br][sw];
                    #pragma unroll
                    for (int sub = 0; sub < 2; sub++) {
                        acc[sub][nt] = __builtin_amdgcn_mfma_f32_16x16x32_bf16(ah[sub][ks], bh, acc[sub][nt], 0, 0, 0);
                        acc[sub][nt] = __builtin_amdgcn_mfma_f32_16x16x32_bf16(ah[sub][ks], bl, acc[sub][nt], 0, 0, 0);
                        acc[sub][nt] = __builtin_amdgcn_mfma_f32_16x16x32_bf16(al[sub][ks], bh, acc[sub][nt], 0, 0, 0);
                    }
                }
            }
        }
    }
    __syncthreads();   // all MFMA LDS reads done before vtr alias writes

    // epilogue: bias + relu; q -> hi/lo, k -> bf16, v -> transpose via LDS.
    // vtr uses its own self-consistent [64][72] layout inside the a_hi
    // storage (8192 shorts >= 4608) -- independent of the main-loop swizzle.
    const float* bias = (y == 0) ? bq : (y == 1) ? bk : bv;
    const int b   = m0 >> 12;
    const int s0b = m0 & 4095;
    unsigned short* vtr = &a_hi[0][0][0];  // alias: [64 d][72]

    #pragma unroll
    for (int sub = 0; sub < 2; sub++)
        #pragma unroll
        for (int nt = 0; nt < 2; nt++) {
            const int col = ch * 32 + nt * 16 + l15;
            const float bb = bias[col];
            const int rloc = rowg * 32 + sub * 16 + quad * 4;
            #pragma unroll
            for (int r = 0; r < 4; r++) {
                float v = fmaxf(acc[sub][nt][r] + bb, 0.f);
                size_t grow = (size_t)(m0 + rloc + r);
                if (y == 0) {
                    unsigned short h = f2bf(v);
                    unsigned short l = f2bf(v - bf2f(h));
                    q_hi[grow * 64 + col] = h;
                    q_lo[grow * 64 + col] = l;
                } else if (y == 1) {
                    k_bf[grow * 64 + col] = f2bf(v);
                } else {
                    vtr[col * 72 + rloc + r] = f2bf(v);  // transpose via LDS
                }
            }
        }
    __syncthreads();   // v-waves' vtr writes visible to storing threads
    if (tid < 512) {
        int row = tid >> 3;          // d 0..63
        int off = (tid & 7) * 8;     // s chunk
        s16x8 vv = *(const s16x8*)&vtr[row * 72 + off];
        *(s16x8*)(vt_g + (size_t)(b * 64 + row) * 4096 + s0b + off) = vv;
    }
}

// ---------------------------------------------------------------------------
// Kernel 3 (v9): fused attention, KVBLK=128, 512-thread blocks owning 256
// q-rows (8 waves x 32q), grid 16x8x4 = 512 = 2 blocks/CU. T14 reg prefetch
// + setprio. LDS 56.3KB.  (unchanged -- measured <40.9us, FETCH clean)
// ---------------------------------------------------------------------------
__global__ __launch_bounds__(512, 2) void attn_kernel(
    const unsigned short* __restrict__ q_hi, const unsigned short* __restrict__ q_lo,
    const unsigned short* __restrict__ k_bf, const unsigned short* __restrict__ vt_g,
    unsigned short* __restrict__ pOb, float* __restrict__ pL)
{
    __shared__ __align__(16) unsigned short kt[128][72];     // [key][dim]
    __shared__ __align__(16) unsigned short vt[64][136];     // [dim][key]  (V^T)
    __shared__ __align__(16) unsigned short pt[8][32][40];   // per-wave P [q][key]

    const int tid  = threadIdx.x;
    const int lane = tid & 63;
    const int w    = tid >> 6;           // 0..7
    const int quad = lane >> 4;
    const int l15  = lane & 15;
    const int ck   = blockIdx.y;         // key chunk (512 keys = 4 tiles x 128)
    const int b    = blockIdx.z;
    const int q0   = blockIdx.x * 256;   // within batch

    // Q fragments for both 16-row subtiles (A layout: m=lane&15, k=quad*8+j)
    const size_t qbase = ((size_t)b * 4096 + q0 + w * 32 + l15) * 64 + quad * 8;
    s16x8 qh[2][2], ql[2][2];            // [sub][k-half]
    #pragma unroll
    for (int sub = 0; sub < 2; sub++) {
        qh[sub][0] = *(const s16x8*)(q_hi + qbase + sub * 1024);
        qh[sub][1] = *(const s16x8*)(q_hi + qbase + sub * 1024 + 32);
        ql[sub][0] = *(const s16x8*)(q_lo + qbase + sub * 1024);
        ql[sub][1] = *(const s16x8*)(q_lo + qbase + sub * 1024 + 32);
    }

    fx4 accO[2][4];
    #pragma unroll
    for (int sub = 0; sub < 2; sub++)
        #pragma unroll
        for (int nt = 0; nt < 4; nt++) accO[sub][nt] = (fx4){0.f, 0.f, 0.f, 0.f};
    float lsum[2][4] = {{0.f, 0.f, 0.f, 0.f}, {0.f, 0.f, 0.f, 0.f}};

    const unsigned short* kgb = k_bf + (size_t)b * 4096 * 64;  // [s][64]
    const unsigned short* vgb = vt_g + (size_t)b * 64 * 4096;  // [d][s]

    // staging: 512 threads; K: rows srow, srow+64 (full 128B rows);
    // V^T: dim srow, key chunks koff, koff+64 (256B contiguous per row/tile)
    const int srow = tid >> 3;            // 0..63
    const int koff = (tid & 7) * 8;       // 16B chunk offset

    const unsigned short* kp = kgb + (size_t)(ck * 512) * 64;   // tile stride 8192
    const unsigned short* vp = vgb + ck * 512;                  // tile stride 128

    // prologue prefetch of super-tile 0 into registers
    s16x8 nk0 = *(const s16x8*)(kp + (size_t)srow * 64 + koff);
    s16x8 nk1 = *(const s16x8*)(kp + (size_t)(srow + 64) * 64 + koff);
    s16x8 nv0 = *(const s16x8*)(vp + (size_t)srow * 4096 + koff);
    s16x8 nv1 = *(const s16x8*)(vp + (size_t)srow * 4096 + koff + 64);

    for (int t = 0; t < 4; t++) {
        // regs -> LDS (prev iter's trailing barrier guarantees readers done)
        *(s16x8*)&kt[srow][koff]      = nk0;
        *(s16x8*)&kt[srow + 64][koff] = nk1;
        *(s16x8*)&vt[srow][koff]      = nv0;
        *(s16x8*)&vt[srow][koff + 64] = nv1;
        __syncthreads();
        // issue next super-tile's loads; latency hides under compute below
        if (t < 3) {
            nk0 = *(const s16x8*)(kp + (size_t)(t + 1) * 8192 + (size_t)srow * 64 + koff);
            nk1 = *(const s16x8*)(kp + (size_t)(t + 1) * 8192 + (size_t)(srow + 64) * 64 + koff);
            nv0 = *(const s16x8*)(vp + (t + 1) * 128 + (size_t)srow * 4096 + koff);
            nv1 = *(const s16x8*)(vp + (t + 1) * 128 + (size_t)srow * 4096 + koff + 64);
        }

        #pragma unroll
        for (int h = 0; h < 2; h++) {
            #pragma unroll
            for (int kh = 0; kh < 2; kh++) {
                // S = Q K^T for this 32-key group; K frags feed both subtiles
                #pragma unroll
                for (int nt2 = 0; nt2 < 2; nt2++) {
                    const int key = h * 64 + kh * 32 + nt2 * 16 + l15;
                    s16x8 k0 = *(const s16x8*)&kt[key][quad * 8];
                    s16x8 k1 = *(const s16x8*)&kt[key][32 + quad * 8];
                    #pragma unroll
                    for (int sub = 0; sub < 2; sub++) {
                        fx4 sc = (fx4){0.f, 0.f, 0.f, 0.f};
                        __builtin_amdgcn_s_setprio(1);
                        sc = __builtin_amdgcn_mfma_f32_16x16x32_bf16(qh[sub][0], k0, sc, 0, 0, 0);
                        sc = __builtin_amdgcn_mfma_f32_16x16x32_bf16(ql[sub][0], k0, sc, 0, 0, 0);
                        sc = __builtin_amdgcn_mfma_f32_16x16x32_bf16(qh[sub][1], k1, sc, 0, 0, 0);
                        sc = __builtin_amdgcn_mfma_f32_16x16x32_bf16(ql[sub][1], k1, sc, 0, 0, 0);
                        __builtin_amdgcn_s_setprio(0);
                        // P = exp(S) -> bf16 -> wave-private LDS (C -> A layout)
                        #pragma unroll
                        for (int r = 0; r < 4; r++) {
                            float p = __builtin_amdgcn_exp2f(sc[r] * LOG2E);
                            unsigned short pb = f2bf(p);
                            lsum[sub][r] += bf2f(pb);   // denominator matches rounded numerator
                            pt[w][sub * 16 + quad * 4 + r][nt2 * 16 + l15] = pb;
                        }
                    }
                }
                // O += P V for this 32-key group; V frags feed both subtiles
                s16x8 pa0 = *(const s16x8*)&pt[w][l15][quad * 8];
                s16x8 pa1 = *(const s16x8*)&pt[w][16 + l15][quad * 8];
                __builtin_amdgcn_s_setprio(1);
                #pragma unroll
                for (int nt = 0; nt < 4; nt++) {
                    s16x8 vf = *(const s16x8*)&vt[nt * 16 + l15][h * 64 + kh * 32 + quad * 8];
                    accO[0][nt] = __builtin_amdgcn_mfma_f32_16x16x32_bf16(pa0, vf, accO[0][nt], 0, 0, 0);
                    accO[1][nt] = __builtin_amdgcn_mfma_f32_16x16x32_bf16(pa1, vf, accO[1][nt], 0, 0, 0);
                }
                __builtin_amdgcn_s_setprio(0);
            }
        }
        __syncthreads();   // this super-tile's readers drained before restage
    }

    // reduce row-sums across the 16 lanes sharing each row group
    #pragma unroll
    for (int sub = 0; sub < 2; sub++)
        #pragma unroll
        for (int r = 0; r < 4; r++) {
            float v = lsum[sub][r];
            #pragma unroll
            for (int o = 1; o < 16; o <<= 1) v += __shfl_xor(v, o);
            lsum[sub][r] = v;
        }
    // write partials: pOb[ck][b*4096+q][64] (bf16), pL[ck][b*4096+q] (fp32)
    #pragma unroll
    for (int sub = 0; sub < 2; sub++)
        #pragma unroll
        for (int r = 0; r < 4; r++) {
            int qrow = q0 + w * 32 + sub * 16 + quad * 4 + r;
            size_t grow = (size_t)b * 4096 + qrow;
            #pragma unroll
            for (int nt = 0; nt < 4; nt++)
                pOb[((size_t)ck * 16384 + grow) * 64 + nt * 16 + l15] = f2bf(accO[sub][nt][r]);
            if (l15 == 0)
                pL[(size_t)ck * 16384 + grow] = lsum[sub][r];
        }
}

// ---------------------------------------------------------------------------
// Kernel 4: combine partials: out = (sum_c pOb) * mask / (sum_c pL)  (unchanged)
// ---------------------------------------------------------------------------
__global__ __launch_bounds__(256) void combine_kernel(
    const unsigned short* __restrict__ pOb, const float* __restrict__ pL,
    const float* __restrict__ mask, float* __restrict__ out)
{
    int idx = blockIdx.x * 256 + threadIdx.x;   // 262144 = (b*4096+s)*16 + dgrp
    int q  = idx >> 4;
    int dg = idx & 15;
    fx4 s = (fx4){0.f, 0.f, 0.f, 0.f};
    float l = 0.f;
    #pragma unroll
    for (int c = 0; c < 8; c++) {
        u16x4 h = *(const u16x4*)(pOb + ((size_t)c * 16384 + q) * 64 + dg * 4);
        s.x += bf2f(h.x);
        s.y += bf2f(h.y);
        s.z += bf2f(h.z);
        s.w += bf2f(h.w);
        l += pL[(size_t)c * 16384 + q];
    }
    float scale = mask[q] / l;
    *(fx4*)(out + (size_t)q * 64 + dg * 4) = s * scale;
}

// ---------------------------------------------------------------------------
extern "C" void kernel_launch(void* const* d_in, const int* in_sizes, int n_in,
                              void* d_out, int out_size, void* d_ws, size_t ws_size,
                              hipStream_t stream)
{
    const float* X    = (const float*)d_in[0];
    const float* mask = (const float*)d_in[1];
    const float* Wq   = (const float*)d_in[2];
    const float* bq   = (const float*)d_in[3];
    const float* Wk   = (const float*)d_in[4];
    const float* bk   = (const float*)d_in[5];
    const float* Wv   = (const float*)d_in[6];
    const float* bv   = (const float*)d_in[7];
    float* out = (float*)d_out;

    char* ws = (char*)d_ws;
    unsigned short* q_hi  = (unsigned short*)(ws);                       // 2 MB
    unsigned short* q_lo  = (unsigned short*)(ws + (size_t)(2u << 20));  // 2 MB
    unsigned short* k_bf  = (unsigned short*)(ws + (size_t)(4u << 20));  // 2 MB
    unsigned short* vt_g  = (unsigned short*)(ws + (size_t)(6u << 20));  // 2 MB  [b][d][s]
    unsigned short* wt_hi = (unsigned short*)(ws + (size_t)(8u << 20));  // 384 KB
    unsigned short* wt_lo = (unsigned short*)(ws + (size_t)(8u << 20) + 393216);
    unsigned short* pOb   = (unsigned short*)(ws + (size_t)(9u << 20));  // 16 MB [8][16384][64] bf16
    float*          pL    = (float*)(ws + (size_t)(25u << 20));          // 512 KB [8][16384]

    hipLaunchKernelGGL(prep_w_kernel, dim3(3, 16), dim3(256), 0, stream,
                       Wq, Wk, Wv, wt_hi, wt_lo);
    hipLaunchKernelGGL(proj_kernel, dim3(256), dim3(768), 0, stream,
                       X, wt_hi, wt_lo, bq, bk, bv, q_hi, q_lo, k_bf, vt_g);
    hipLaunchKernelGGL(attn_kernel, dim3(16, 8, 4), dim3(512), 0, stream,
                       q_hi, q_lo, k_bf, vt_g, pOb, pL);
    hipLaunchKernelGGL(combine_kernel, dim3(1024), dim3(256), 0, stream,
                       pOb, pL, mask, out);
}